// Round 1
// baseline (352.182 us; speedup 1.0000x reference)
//
#include <hip/hip_runtime.h>
#include <math.h>

// s = sum_i R[i] * ||Z[i,:]||^2 ;  out = 1 - exp(-exp(s))
// Z: (500000, 128) fp32, R: (500000,) fp32, out: scalar fp32.
// Memory-bound: 258 MB read -> ~41 us roofline at 6.3 TB/s.

#define NROWS 500000
#define DCOLS 128
#define TOTAL4 (NROWS * (DCOLS / 4))   // 16,000,000 float4 elements

__global__ void __launch_bounds__(256)
bp_reduce(const float* __restrict__ Z, const float* __restrict__ R,
          float* __restrict__ partial) {
    const float4* __restrict__ Z4 = (const float4*)Z;
    int tid = blockIdx.x * blockDim.x + threadIdx.x;
    int stride = gridDim.x * blockDim.x;

    float acc = 0.0f;
    for (int i = tid; i < TOTAL4; i += stride) {
        float4 v = Z4[i];
        // float4 index i covers elements [4i, 4i+4) -> row = (4i)/128 = i>>5.
        // 32 consecutive lanes share one row: R load is wave-coherent (L1 hit).
        float w = R[i >> 5];
        acc += w * (v.x * v.x + v.y * v.y + v.z * v.z + v.w * v.w);
    }

    // wave(64)-level shuffle reduction
    #pragma unroll
    for (int off = 32; off > 0; off >>= 1)
        acc += __shfl_down(acc, off, 64);

    __shared__ float smem[4];            // 256 threads = 4 waves
    int wave = threadIdx.x >> 6;
    int lane = threadIdx.x & 63;
    if (lane == 0) smem[wave] = acc;
    __syncthreads();

    if (threadIdx.x == 0) {
        float s = smem[0] + smem[1] + smem[2] + smem[3];
        atomicAdd(partial, s);           // device-scope by default on CDNA
    }
}

__global__ void bp_finalize(const float* __restrict__ partial,
                            float* __restrict__ out) {
    float s = *partial;
    float lam = expf(s);
    out[0] = 1.0f - expf(-lam);
}

extern "C" void kernel_launch(void* const* d_in, const int* in_sizes, int n_in,
                              void* d_out, int out_size, void* d_ws, size_t ws_size,
                              hipStream_t stream) {
    const float* Z = (const float*)d_in[0];
    const float* R = (const float*)d_in[1];
    float* out = (float*)d_out;
    float* partial = (float*)d_ws;

    // d_ws is re-poisoned to 0xAA before every timed launch -> must zero it.
    hipMemsetAsync(partial, 0, sizeof(float), stream);

    const int block = 256;
    const int grid = 4096;               // 16 blocks/CU worth of waves; grid-stride
    bp_reduce<<<grid, block, 0, stream>>>(Z, R, partial);
    bp_finalize<<<1, 1, 0, stream>>>(partial, out);
}

// Round 3
// 320.007 us; speedup vs baseline: 1.1005x; 1.1005x over previous
//
#include <hip/hip_runtime.h>
#include <math.h>

// s = sum_i R[i] * ||Z[i,:]||^2 ;  out = 1 - exp(-exp(s))
// Z: (500000,128) fp32 = 256 MB (streamed once), R: 2 MB (L2-resident).
// Memory-bound: 258 MB read -> ~41 us floor at 6.3 TB/s achievable.

#define NROWS   500000
#define DCOLS   128
#define N4      (NROWS * DCOLS / 4)   // 16,000,000 float4
#define BLOCK   256
#define GRID    2500
#define NTHREADS (GRID * BLOCK)       // 640,000 -> exactly 25 float4/thread
#define OUTER   5
#define INNER   5                     // OUTER*INNER = 25

// native clang vector (not HIP_vector_type struct) so nontemporal builtin accepts it
typedef float floatx4 __attribute__((ext_vector_type(4)));

__global__ void __launch_bounds__(BLOCK)
bp_reduce(const float* __restrict__ Z, const float* __restrict__ R,
          float* __restrict__ partial) {
    const floatx4* __restrict__ Z4 = (const floatx4*)Z;
    const int tid = blockIdx.x * BLOCK + threadIdx.x;

    float acc = 0.0f;
    int i = tid;
    #pragma unroll
    for (int o = 0; o < OUTER; ++o) {
        floatx4 v[INNER];
        float   w[INNER];
        // 5 independent 16B loads in flight (known trip count -> fully unrolled)
        #pragma unroll
        for (int u = 0; u < INNER; ++u) {
            const int idx = i + u * NTHREADS;
            v[u] = __builtin_nontemporal_load(&Z4[idx]);  // Z streamed once: bypass cache fill
            w[u] = R[idx >> 5];   // float4 idx -> row = (4*idx)/128; 32 lanes share -> broadcast
        }
        #pragma unroll
        for (int u = 0; u < INNER; ++u)
            acc += w[u] * (v[u].x * v[u].x + v[u].y * v[u].y +
                           v[u].z * v[u].z + v[u].w * v[u].w);
        i += INNER * NTHREADS;
    }

    // wave(64) shuffle reduction
    #pragma unroll
    for (int off = 32; off > 0; off >>= 1)
        acc += __shfl_down(acc, off, 64);

    __shared__ float smem[BLOCK / 64];
    const int wave = threadIdx.x >> 6;
    const int lane = threadIdx.x & 63;
    if (lane == 0) smem[wave] = acc;
    __syncthreads();

    if (threadIdx.x == 0)
        partial[blockIdx.x] = smem[0] + smem[1] + smem[2] + smem[3];
        // unconditional write per block: no zero-init of d_ws needed
}

__global__ void __launch_bounds__(BLOCK)
bp_finalize(const float* __restrict__ partial, float* __restrict__ out) {
    float acc = 0.0f;
    for (int i = threadIdx.x; i < GRID; i += BLOCK)
        acc += partial[i];

    #pragma unroll
    for (int off = 32; off > 0; off >>= 1)
        acc += __shfl_down(acc, off, 64);

    __shared__ float smem[BLOCK / 64];
    const int wave = threadIdx.x >> 6;
    const int lane = threadIdx.x & 63;
    if (lane == 0) smem[wave] = acc;
    __syncthreads();

    if (threadIdx.x == 0) {
        float s = smem[0] + smem[1] + smem[2] + smem[3];
        float lam = expf(s);
        out[0] = 1.0f - expf(-lam);
    }
}

extern "C" void kernel_launch(void* const* d_in, const int* in_sizes, int n_in,
                              void* d_out, int out_size, void* d_ws, size_t ws_size,
                              hipStream_t stream) {
    const float* Z = (const float*)d_in[0];
    const float* R = (const float*)d_in[1];
    float* out = (float*)d_out;
    float* partial = (float*)d_ws;   // 2500 floats = 10 KB << ws_size

    bp_reduce<<<GRID, BLOCK, 0, stream>>>(Z, R, partial);
    bp_finalize<<<1, BLOCK, 0, stream>>>(partial, out);
}